// Round 1
// baseline (3640.657 us; speedup 1.0000x reference)
//
#include <hip/hip_runtime.h>
#include <hip/hip_bf16.h>
#include <cstdint>
#include <cstddef>

// Problem constants
#define NB   8      // batch
#define NCHN 256    // C
#define NSP  1024   // N (spatial)
#define NKK  16     // K (neighbourhood)
#define NCQ  64     // C/4
#define NPK  16384  // NSP*NKK pixels per (b)
#define NBK  128    // NB*NKK planes

typedef __hip_bfloat16 bf16;

__device__ __forceinline__ float bf2f(bf16 v) { return __bfloat162float(v); }

// ---------------- P0: W2 = t_w @ v_w   (u = W2@x + ub,  ub = t_w @ v_b) -----
__global__ __launch_bounds__(256) void k_w2(const float* __restrict__ t_w,
                                            const float* __restrict__ v_w,
                                            const float* __restrict__ v_b,
                                            float* __restrict__ w2,
                                            float* __restrict__ ub) {
  const int o = blockIdx.x;   // 0..255
  const int c = threadIdx.x;  // 0..255
  __shared__ float trow[NCHN];
  __shared__ float red[NCHN];
  trow[c] = t_w[o * NCHN + c];
  __syncthreads();
  float acc = 0.f;
  for (int m = 0; m < NCHN; ++m) acc = fmaf(trow[m], v_w[m * NCHN + c], acc);
  w2[o * NCHN + c] = acc;
  red[c] = trow[c] * v_b[c];
  __syncthreads();
  for (int s = 128; s > 0; s >>= 1) {
    if (c < s) red[c] += red[c + s];
    __syncthreads();
  }
  if (c == 0) ub[o] = red[0];
}

// ---------------- zero helper ----------------
__global__ void k_zero(float* __restrict__ p, int n) {
  int i = blockIdx.x * 256 + threadIdx.x;
  if (i < n) p[i] = 0.f;
}

// ---------------- P1: fused projections ----------------
// For each b: Y[o,p] = sum_c W(o,c) * x[b,c,p], p = n*16+kk, o in [0,640):
//   o<64: q_w -> q[bk][n][d]; o<128: k_w -> kT[bk][d][n];
//   o<384: W2  -> u[bk][c][n] (+ub, bf16); o<640: t_w -> s[b][c][p] (bf16)
// grid (256 p-tiles, 10 o-tiles, NB), block 256
__global__ __launch_bounds__(256) void k_proj(
    const float* __restrict__ x, const float* __restrict__ q_w,
    const float* __restrict__ k_w, const float* __restrict__ w2,
    const float* __restrict__ t_w, const float* __restrict__ ub,
    float* __restrict__ q, float* __restrict__ kT,
    bf16* __restrict__ u, bf16* __restrict__ s) {
  const int p0 = blockIdx.x * 64;
  const int o0 = blockIdx.y * 64;
  const int b  = blockIdx.z;
  const int t  = threadIdx.x;
  const int og = t & 15, pg = t >> 4;
  __shared__ float wtT[64][65];  // [c-local][o-local], padded: conflict-free transposed stores
  __shared__ float xt[64][64];   // [c-local][p-local]
  float acc[4][4] = {};
  const float* xb = x + (size_t)b * NCHN * NPK;
  for (int c0 = 0; c0 < NCHN; c0 += 64) {
    for (int idx = t; idx < 4096; idx += 256) {
      const int i = idx >> 6, j = idx & 63;  // i=o-local, j=c-local
      const int o = o0 + i;
      float wv;
      if (o < 64)       wv = q_w[o * NCHN + c0 + j];
      else if (o < 128) wv = k_w[(o - 64) * NCHN + c0 + j];
      else if (o < 384) wv = w2[(o - 128) * NCHN + c0 + j];
      else              wv = t_w[(o - 384) * NCHN + c0 + j];
      wtT[j][i] = wv;
    }
    for (int idx = t; idx < 4096; idx += 256) {
      const int i = idx >> 6, j = idx & 63;  // i=c-local, j=p-local
      xt[i][j] = xb[(size_t)(c0 + i) * NPK + p0 + j];
    }
    __syncthreads();
    #pragma unroll 8
    for (int kx = 0; kx < 64; ++kx) {
      float a[4], bb[4];
      #pragma unroll
      for (int i = 0; i < 4; ++i) a[i] = wtT[kx][og * 4 + i];
      #pragma unroll
      for (int j = 0; j < 4; ++j) bb[j] = xt[kx][pg * 4 + j];
      #pragma unroll
      for (int i = 0; i < 4; ++i)
        #pragma unroll
        for (int j = 0; j < 4; ++j) acc[i][j] = fmaf(a[i], bb[j], acc[i][j]);
    }
    __syncthreads();
  }
  // epilogue: scatter by destination layout
  #pragma unroll
  for (int i = 0; i < 4; ++i) {
    const int o = o0 + og * 4 + i;
    #pragma unroll
    for (int j = 0; j < 4; ++j) {
      const int p = p0 + pg * 4 + j;
      const int n = p >> 4, kk = p & 15;
      const float v = acc[i][j];
      if (o < 64) {
        q[(((size_t)b * NKK + kk) * NSP + n) * NCQ + o] = v;
      } else if (o < 128) {
        kT[(((size_t)b * NKK + kk) * NCQ + (o - 64)) * NSP + n] = v;
      } else if (o < 384) {
        const int c = o - 128;
        u[(((size_t)b * NKK + kk) * NCHN + c) * NSP + n] = __float2bfloat16(v + ub[c]);
      } else {
        const int c = o - 384;
        s[((size_t)b * NCHN + c) * NPK + p] = __float2bfloat16(v);
      }
    }
  }
}

// ---------------- P2a: softmax row stats (online) ----------------
// grid (16 n-tiles, NBK), block 256
__global__ __launch_bounds__(256) void k_stats(
    const float* __restrict__ q, const float* __restrict__ kT,
    float* __restrict__ m_i, float* __restrict__ inv_l) {
  const int n0 = blockIdx.x * 64;
  const int bk = blockIdx.y;
  const int t  = threadIdx.x;
  const int g0 = t & 15, g1 = t >> 4;
  __shared__ float qtT[64][65];  // [d][n-local]
  __shared__ float kt[64][64];   // [d][m-local]
  __shared__ float rmax[64], rsum[64];
  __shared__ float redm[64][17], reds[64][17];
  const float* qp = q + (size_t)bk * NSP * NCQ;
  const float* kp = kT + (size_t)bk * NCQ * NSP;
  for (int idx = t; idx < 4096; idx += 256) {
    const int i = idx >> 6, j = idx & 63;  // i=n-local, j=d
    qtT[j][i] = qp[(size_t)(n0 + i) * NCQ + j];
  }
  if (t < 64) { rmax[t] = -1e30f; rsum[t] = 0.f; }
  __syncthreads();
  for (int mt = 0; mt < 16; ++mt) {
    for (int idx = t; idx < 4096; idx += 256) {
      const int i = idx >> 6, j = idx & 63;
      kt[i][j] = kp[(size_t)i * NSP + mt * 64 + j];
    }
    __syncthreads();
    float e[4][4] = {};
    for (int d = 0; d < 64; ++d) {
      float a[4], bb[4];
      #pragma unroll
      for (int i = 0; i < 4; ++i) a[i] = qtT[d][g0 * 4 + i];
      #pragma unroll
      for (int j = 0; j < 4; ++j) bb[j] = kt[d][g1 * 4 + j];
      #pragma unroll
      for (int i = 0; i < 4; ++i)
        #pragma unroll
        for (int j = 0; j < 4; ++j) e[i][j] = fmaf(a[i], bb[j], e[i][j]);
    }
    #pragma unroll
    for (int i = 0; i < 4; ++i) {
      float mx = fmaxf(fmaxf(e[i][0], e[i][1]), fmaxf(e[i][2], e[i][3]));
      redm[g0 * 4 + i][g1] = mx;
    }
    __syncthreads();
    if (t < 64) {
      float mx = rmax[t];
      for (int g = 0; g < 16; ++g) mx = fmaxf(mx, redm[t][g]);
      rsum[t] *= __expf(rmax[t] - mx);  // first tile: 0 * exp(-inf) = 0
      rmax[t] = mx;
    }
    __syncthreads();
    #pragma unroll
    for (int i = 0; i < 4; ++i) {
      const int n = g0 * 4 + i;
      const float mxn = rmax[n];
      float ssum = __expf(e[i][0] - mxn) + __expf(e[i][1] - mxn) +
                   __expf(e[i][2] - mxn) + __expf(e[i][3] - mxn);
      reds[n][g1] = ssum;
    }
    __syncthreads();
    if (t < 64) {
      float ssum = 0.f;
      for (int g = 0; g < 16; ++g) ssum += reds[t][g];
      rsum[t] += ssum;
    }
    __syncthreads();
  }
  if (t < 64) {
    m_i[(size_t)bk * NSP + n0 + t] = rmax[t];
    inv_l[(size_t)bk * NSP + n0 + t] = 1.0f / rsum[t];
  }
}

// ---------------- P2b: inv_denom[b,n,m] = 1/(1e-9 + sum_k softmax_k[n,m]) ---
// grid (16 m-tiles, 16 n-tiles, NB), block 256
__global__ __launch_bounds__(256) void k_denom(
    const float* __restrict__ q, const float* __restrict__ kT,
    const float* __restrict__ m_i, const float* __restrict__ inv_l,
    float* __restrict__ invden) {
  const int m0 = blockIdx.x * 64, n0 = blockIdx.y * 64, b = blockIdx.z;
  const int t = threadIdx.x;
  const int g0 = t & 15, g1 = t >> 4;
  __shared__ float qtT[64][65];
  __shared__ float kt[64][64];
  __shared__ float sm[64], sl[64];
  float den[4][4] = {};
  for (int kk = 0; kk < NKK; ++kk) {
    const int bk = b * NKK + kk;
    const float* qp = q + (size_t)bk * NSP * NCQ;
    const float* kp = kT + (size_t)bk * NCQ * NSP;
    for (int idx = t; idx < 4096; idx += 256) {
      const int i = idx >> 6, j = idx & 63;
      qtT[j][i] = qp[(size_t)(n0 + i) * NCQ + j];
    }
    for (int idx = t; idx < 4096; idx += 256) {
      const int i = idx >> 6, j = idx & 63;
      kt[i][j] = kp[(size_t)i * NSP + m0 + j];
    }
    if (t < 64) {
      sm[t] = m_i[(size_t)bk * NSP + n0 + t];
      sl[t] = inv_l[(size_t)bk * NSP + n0 + t];
    }
    __syncthreads();
    float e[4][4] = {};
    for (int d = 0; d < 64; ++d) {
      float a[4], bb[4];
      #pragma unroll
      for (int i = 0; i < 4; ++i) a[i] = qtT[d][g0 * 4 + i];
      #pragma unroll
      for (int j = 0; j < 4; ++j) bb[j] = kt[d][g1 * 4 + j];
      #pragma unroll
      for (int i = 0; i < 4; ++i)
        #pragma unroll
        for (int j = 0; j < 4; ++j) e[i][j] = fmaf(a[i], bb[j], e[i][j]);
    }
    #pragma unroll
    for (int i = 0; i < 4; ++i) {
      const float mx = sm[g0 * 4 + i], il = sl[g0 * 4 + i];
      #pragma unroll
      for (int j = 0; j < 4; ++j)
        den[i][j] += __expf(e[i][j] - mx) * il;
    }
    __syncthreads();
  }
  #pragma unroll
  for (int i = 0; i < 4; ++i)
    #pragma unroll
    for (int j = 0; j < 4; ++j)
      invden[(size_t)b * NSP * NSP + (size_t)(n0 + g0 * 4 + i) * NSP + m0 + g1 * 4 + j] =
          1.0f / (1e-9f + den[i][j]);
}

// ---------------- P3: TxR[bk][c][m] = sum_n u[bk][c][n] * Atilde[n][m] -------
// Atilde recomputed from E; grid (16 m-tiles, NBK), block 256
__global__ __launch_bounds__(256) void k_xr(
    const float* __restrict__ q, const float* __restrict__ kT,
    const bf16* __restrict__ u, const float* __restrict__ m_i,
    const float* __restrict__ inv_l, const float* __restrict__ invden,
    float* __restrict__ txr) {
  const int m0 = blockIdx.x * 64;
  const int bk = blockIdx.y;
  const int b  = bk >> 4;
  const int t  = threadIdx.x;
  const int g0 = t & 15, g1 = t >> 4;
  __shared__ float kt[64][64];   // [d][m-local]
  __shared__ float buf[64][65];  // qtT [d][n-local]  then utT [n-local][c-local]
  __shared__ float At[64][65];   // [n-local][m-local]
  __shared__ float sm[64], sl[64];
  float acc[4][4][4] = {};       // [cc][c-sub][m-sub]
  const float* qp = q + (size_t)bk * NSP * NCQ;
  const float* kp = kT + (size_t)bk * NCQ * NSP;
  const bf16*  up = u + (size_t)bk * NCHN * NSP;
  const float* dp = invden + (size_t)b * NSP * NSP;
  for (int idx = t; idx < 4096; idx += 256) {
    const int i = idx >> 6, j = idx & 63;
    kt[i][j] = kp[(size_t)i * NSP + m0 + j];
  }
  for (int nt = 0; nt < 16; ++nt) {
    const int n0 = nt * 64;
    for (int idx = t; idx < 4096; idx += 256) {
      const int i = idx >> 6, j = idx & 63;  // i=n-local, j=d
      buf[j][i] = qp[(size_t)(n0 + i) * NCQ + j];
    }
    if (t < 64) {
      sm[t] = m_i[(size_t)bk * NSP + n0 + t];
      sl[t] = inv_l[(size_t)bk * NSP + n0 + t];
    }
    __syncthreads();
    float e[4][4] = {};
    for (int d = 0; d < 64; ++d) {
      float a[4], bb[4];
      #pragma unroll
      for (int i = 0; i < 4; ++i) a[i] = buf[d][g0 * 4 + i];
      #pragma unroll
      for (int j = 0; j < 4; ++j) bb[j] = kt[d][g1 * 4 + j];
      #pragma unroll
      for (int i = 0; i < 4; ++i)
        #pragma unroll
        for (int j = 0; j < 4; ++j) e[i][j] = fmaf(a[i], bb[j], e[i][j]);
    }
    #pragma unroll
    for (int i = 0; i < 4; ++i) {
      const int n = g0 * 4 + i;
      const float mx = sm[n], il = sl[n];
      #pragma unroll
      for (int j = 0; j < 4; ++j) {
        const int m = g1 * 4 + j;
        const float pj = __expf(e[i][j] - mx) * il;
        At[n][m] = pj * dp[(size_t)(n0 + n) * NSP + m0 + m];
      }
    }
    __syncthreads();
    for (int cc = 0; cc < 4; ++cc) {
      for (int idx = t; idx < 4096; idx += 256) {
        const int i = idx >> 6, j = idx & 63;  // i=c-local, j=n-local
        buf[j][i] = bf2f(up[(size_t)(cc * 64 + i) * NSP + n0 + j]);
      }
      __syncthreads();
      #pragma unroll 4
      for (int nn = 0; nn < 64; ++nn) {
        float a[4], bb[4];
        #pragma unroll
        for (int i = 0; i < 4; ++i) a[i] = buf[nn][g0 * 4 + i];
        #pragma unroll
        for (int j = 0; j < 4; ++j) bb[j] = At[nn][g1 * 4 + j];
        #pragma unroll
        for (int i = 0; i < 4; ++i)
          #pragma unroll
          for (int j = 0; j < 4; ++j)
            acc[cc][i][j] = fmaf(a[i], bb[j], acc[cc][i][j]);
      }
      __syncthreads();
    }
  }
  #pragma unroll
  for (int cc = 0; cc < 4; ++cc)
    #pragma unroll
    for (int i = 0; i < 4; ++i) {
      const int cch = cc * 64 + g0 * 4 + i;
      #pragma unroll
      for (int j = 0; j < 4; ++j)
        txr[((size_t)bk * NCHN + cch) * NSP + m0 + g1 * 4 + j] = acc[cc][i][j];
    }
}

// ---------------- P4a: BN partial sums over t = s + t_b - TxR ----------------
// grid (NCHN, NB), block 256
__global__ __launch_bounds__(256) void k_bnstats(
    const bf16* __restrict__ s, const float* __restrict__ txr,
    const float* __restrict__ t_b, float* __restrict__ bnsum,
    float* __restrict__ bnsq) {
  const int c = blockIdx.x, b = blockIdx.y, t = threadIdx.x;
  __shared__ float tx[16 * 273];
  __shared__ float r1[256], r2[256];
  const bf16* sp = s + ((size_t)b * NCHN + c) * NPK;
  const float tb = t_b[c];
  float lsum = 0.f, lss = 0.f;
  for (int n0 = 0; n0 < NSP; n0 += 256) {
    for (int idx = t; idx < 4096; idx += 256) {
      const int kk = idx >> 8, nn = idx & 255;
      tx[kk * 273 + nn] = txr[(((size_t)b * NKK + kk) * NCHN + c) * NSP + n0 + nn];
    }
    __syncthreads();
    for (int idx = t; idx < 4096; idx += 256) {
      const int nn = idx >> 4, kk = idx & 15;
      const float tv = bf2f(sp[n0 * NKK + idx]) + tb - tx[kk * 273 + nn];
      lsum += tv;
      lss = fmaf(tv, tv, lss);
    }
    __syncthreads();
  }
  r1[t] = lsum; r2[t] = lss;
  __syncthreads();
  for (int sh = 128; sh > 0; sh >>= 1) {
    if (t < sh) { r1[t] += r1[t + sh]; r2[t] += r2[t + sh]; }
    __syncthreads();
  }
  if (t == 0) {
    atomicAdd(&bnsum[c], r1[0]);
    atomicAdd(&bnsq[c], r2[0]);
  }
}

// ---------------- P4b: finalize BN affine ----------------
__global__ void k_bnfin(const float* __restrict__ bnsum, const float* __restrict__ bnsq,
                        const float* __restrict__ gamma, const float* __restrict__ beta,
                        float* __restrict__ abuf, float* __restrict__ bbuf) {
  const int c = threadIdx.x;  // 256
  const float inv_m = 1.0f / 131072.0f;
  const float mean = bnsum[c] * inv_m;
  const float var = bnsq[c] * inv_m - mean * mean;
  const float a = gamma[c] * rsqrtf(var + 1e-5f);
  abuf[c] = a;
  bbuf[c] = beta[c] - mean * a;
}

// ---------------- P4c: out = x + relu(a*t + bb) ----------------
// grid (NCHN, NB), block 256
__global__ __launch_bounds__(256) void k_out(
    const float* __restrict__ x, const bf16* __restrict__ s,
    const float* __restrict__ txr, const float* __restrict__ t_b,
    const float* __restrict__ abuf, const float* __restrict__ bbuf,
    float* __restrict__ out) {
  const int c = blockIdx.x, b = blockIdx.y, t = threadIdx.x;
  __shared__ float tx[16 * 273];
  const bf16* sp = s + ((size_t)b * NCHN + c) * NPK;
  const float* xp = x + ((size_t)b * NCHN + c) * NPK;
  float* op = out + ((size_t)b * NCHN + c) * NPK;
  const float tb = t_b[c], a = abuf[c], bb = bbuf[c];
  for (int n0 = 0; n0 < NSP; n0 += 256) {
    for (int idx = t; idx < 4096; idx += 256) {
      const int kk = idx >> 8, nn = idx & 255;
      tx[kk * 273 + nn] = txr[(((size_t)b * NKK + kk) * NCHN + c) * NSP + n0 + nn];
    }
    __syncthreads();
    for (int idx = t; idx < 4096; idx += 256) {
      const int nn = idx >> 4, kk = idx & 15;
      const float tv = bf2f(sp[n0 * NKK + idx]) + tb - tx[kk * 273 + nn];
      const float r = fmaxf(fmaf(tv, a, bb), 0.f);
      op[n0 * NKK + idx] = xp[n0 * NKK + idx] + r;
    }
    __syncthreads();
  }
}

extern "C" void kernel_launch(void* const* d_in, const int* in_sizes, int n_in,
                              void* d_out, int out_size, void* d_ws, size_t ws_size,
                              hipStream_t stream) {
  (void)in_sizes; (void)n_in; (void)out_size; (void)ws_size;
  const float* x     = (const float*)d_in[0];
  const float* q_w   = (const float*)d_in[1];
  const float* k_w   = (const float*)d_in[2];
  const float* v_w   = (const float*)d_in[3];
  const float* v_b   = (const float*)d_in[4];
  const float* t_w   = (const float*)d_in[5];
  const float* t_b   = (const float*)d_in[6];
  const float* gamma = (const float*)d_in[7];
  const float* beta  = (const float*)d_in[8];
  float* out = (float*)d_out;

  // workspace carve (bytes)
  char* w = (char*)d_ws;
  float* q      = (float*)w; w += (size_t)NBK * NSP * NCQ * 4;     // 33.5 MB
  float* kT     = (float*)w; w += (size_t)NBK * NCQ * NSP * 4;     // 33.5 MB
  float* invden = (float*)w; w += (size_t)NB * NSP * NSP * 4;      // 33.5 MB
  float* txr    = (float*)w; w += (size_t)NBK * NCHN * NSP * 4;    // 134 MB
  bf16*  u      = (bf16*)w;  w += (size_t)NBK * NCHN * NSP * 2;    // 67 MB
  bf16*  s      = (bf16*)w;  w += (size_t)NB * NCHN * NPK * 2;     // 67 MB
  float* m_i    = (float*)w; w += (size_t)NBK * NSP * 4;
  float* inv_l  = (float*)w; w += (size_t)NBK * NSP * 4;
  float* w2     = (float*)w; w += (size_t)NCHN * NCHN * 4;
  float* ub     = (float*)w; w += 1024;
  float* bnsum  = (float*)w; w += 1024;  // 256 used; adjacent to bnsq
  float* bnsq   = (float*)w; w += 1024;
  float* abuf   = (float*)w; w += 1024;
  float* bbuf   = (float*)w; w += 1024;

  k_zero<<<dim3(2), dim3(256), 0, stream>>>(bnsum, 512);  // zeroes bnsum + bnsq
  k_w2<<<dim3(256), dim3(256), 0, stream>>>(t_w, v_w, v_b, w2, ub);
  k_proj<<<dim3(NPK / 64, 10, NB), dim3(256), 0, stream>>>(
      x, q_w, k_w, w2, t_w, ub, q, kT, u, s);
  k_stats<<<dim3(16, NBK), dim3(256), 0, stream>>>(q, kT, m_i, inv_l);
  k_denom<<<dim3(16, 16, NB), dim3(256), 0, stream>>>(q, kT, m_i, inv_l, invden);
  k_xr<<<dim3(16, NBK), dim3(256), 0, stream>>>(q, kT, u, m_i, inv_l, invden, txr);
  k_bnstats<<<dim3(NCHN, NB), dim3(256), 0, stream>>>(s, txr, t_b, bnsum, bnsq);
  k_bnfin<<<dim3(1), dim3(256), 0, stream>>>(bnsum, bnsq, gamma, beta, abuf, bbuf);
  k_out<<<dim3(NCHN, NB), dim3(256), 0, stream>>>(x, s, txr, t_b, abuf, bbuf, out);
}

// Round 2
// 1699.960 us; speedup vs baseline: 2.1416x; 2.1416x over previous
//
#include <hip/hip_runtime.h>
#include <hip/hip_bf16.h>
#include <cstdint>
#include <cstddef>

// Problem constants
#define NB   8      // batch
#define NCHN 256    // C
#define NSP  1024   // N (spatial)
#define NKK  16     // K (neighbourhood)
#define NCQ  64     // C/4
#define NPK  16384  // NSP*NKK pixels per (b)
#define NBK  128    // NB*NKK planes

typedef __hip_bfloat16 bf16;
typedef unsigned short u16;
typedef __attribute__((ext_vector_type(8))) short bf16x8;
typedef __attribute__((ext_vector_type(4))) float f32x4;

__device__ __forceinline__ float bf2f(bf16 v) { return __bfloat162float(v); }

// raw bf16 (RNE) from float, and back
__device__ __forceinline__ u16 f2bf(float x) {
  unsigned b = __float_as_uint(x);
  return (u16)((b + 0x7FFF + ((b >> 16) & 1)) >> 16);
}
__device__ __forceinline__ float bfr2f(u16 u) { return __uint_as_float(((unsigned)u) << 16); }

// stage a contiguous [64 rows][64 u16] global tile into LDS [64][72] (pad 16B)
__device__ __forceinline__ void stage64(const u16* __restrict__ g, u16* __restrict__ l, int t) {
  #pragma unroll
  for (int i = 0; i < 2; ++i) {
    const int idx = t + i * 256;
    const int row = idx >> 3, col = (idx & 7) * 8;
    const bf16x8 v = *reinterpret_cast<const bf16x8*>(g + (size_t)row * 64 + col);
    *reinterpret_cast<bf16x8*>(l + row * 72 + col) = v;
  }
}

// ---------------- P0: W2 = t_w @ v_w   (u = W2@x + ub,  ub = t_w @ v_b) -----
__global__ __launch_bounds__(256) void k_w2(const float* __restrict__ t_w,
                                            const float* __restrict__ v_w,
                                            const float* __restrict__ v_b,
                                            float* __restrict__ w2,
                                            float* __restrict__ ub) {
  const int o = blockIdx.x;   // 0..255
  const int c = threadIdx.x;  // 0..255
  __shared__ float trow[NCHN];
  __shared__ float red[NCHN];
  trow[c] = t_w[o * NCHN + c];
  __syncthreads();
  float acc = 0.f;
  for (int m = 0; m < NCHN; ++m) acc = fmaf(trow[m], v_w[m * NCHN + c], acc);
  w2[o * NCHN + c] = acc;
  red[c] = trow[c] * v_b[c];
  __syncthreads();
  for (int s = 128; s > 0; s >>= 1) {
    if (c < s) red[c] += red[c + s];
    __syncthreads();
  }
  if (c == 0) ub[o] = red[0];
}

// ---------------- zero helper ----------------
__global__ void k_zero(float* __restrict__ p, int n) {
  int i = blockIdx.x * 256 + threadIdx.x;
  if (i < n) p[i] = 0.f;
}

// ---------------- P1: fused projections ----------------
// o<64: q -> qh/ql[bk][n][d] (split bf16); o<128: k -> kh/kl[bk][m][d];
// o<384: W2 -> u[bk][c][n] (+ub, bf16); o<640: t_w -> s[b][c][p] (bf16)
__global__ __launch_bounds__(256) void k_proj(
    const float* __restrict__ x, const float* __restrict__ q_w,
    const float* __restrict__ k_w, const float* __restrict__ w2,
    const float* __restrict__ t_w, const float* __restrict__ ub,
    u16* __restrict__ qh, u16* __restrict__ ql,
    u16* __restrict__ kh, u16* __restrict__ kl,
    bf16* __restrict__ u, bf16* __restrict__ s) {
  const int p0 = blockIdx.x * 64;
  const int o0 = blockIdx.y * 64;
  const int b  = blockIdx.z;
  const int t  = threadIdx.x;
  const int og = t & 15, pg = t >> 4;
  __shared__ float wtT[64][65];
  __shared__ float xt[64][64];
  float acc[4][4] = {};
  const float* xb = x + (size_t)b * NCHN * NPK;
  for (int c0 = 0; c0 < NCHN; c0 += 64) {
    for (int idx = t; idx < 4096; idx += 256) {
      const int i = idx >> 6, j = idx & 63;
      const int o = o0 + i;
      float wv;
      if (o < 64)       wv = q_w[o * NCHN + c0 + j];
      else if (o < 128) wv = k_w[(o - 64) * NCHN + c0 + j];
      else if (o < 384) wv = w2[(o - 128) * NCHN + c0 + j];
      else              wv = t_w[(o - 384) * NCHN + c0 + j];
      wtT[j][i] = wv;
    }
    for (int idx = t; idx < 4096; idx += 256) {
      const int i = idx >> 6, j = idx & 63;
      xt[i][j] = xb[(size_t)(c0 + i) * NPK + p0 + j];
    }
    __syncthreads();
    #pragma unroll 8
    for (int kx = 0; kx < 64; ++kx) {
      float a[4], bb[4];
      #pragma unroll
      for (int i = 0; i < 4; ++i) a[i] = wtT[kx][og * 4 + i];
      #pragma unroll
      for (int j = 0; j < 4; ++j) bb[j] = xt[kx][pg * 4 + j];
      #pragma unroll
      for (int i = 0; i < 4; ++i)
        #pragma unroll
        for (int j = 0; j < 4; ++j) acc[i][j] = fmaf(a[i], bb[j], acc[i][j]);
    }
    __syncthreads();
  }
  #pragma unroll
  for (int i = 0; i < 4; ++i) {
    const int o = o0 + og * 4 + i;
    #pragma unroll
    for (int j = 0; j < 4; ++j) {
      const int p = p0 + pg * 4 + j;
      const int n = p >> 4, kk = p & 15;
      const float v = acc[i][j];
      if (o < 64) {
        const size_t base = (((size_t)b * NKK + kk) * NSP + n) * NCQ + o;
        const u16 hi = f2bf(v);
        qh[base] = hi;
        ql[base] = f2bf(v - bfr2f(hi));
      } else if (o < 128) {
        const size_t base = (((size_t)b * NKK + kk) * NSP + n) * NCQ + (o - 64);
        const u16 hi = f2bf(v);
        kh[base] = hi;
        kl[base] = f2bf(v - bfr2f(hi));
      } else if (o < 384) {
        const int c = o - 128;
        u[(((size_t)b * NKK + kk) * NCHN + c) * NSP + n] = __float2bfloat16(v + ub[c]);
      } else {
        const int c = o - 384;
        s[((size_t)b * NCHN + c) * NPK + p] = __float2bfloat16(v);
      }
    }
  }
}

// ---------------- P2a: softmax row stats via split-bf16 MFMA ----------------
// grid (16 n-tiles, NBK), block 256 (4 waves; wave w -> n rows w*16..w*16+16)
__global__ __launch_bounds__(256) void k_stats(
    const u16* __restrict__ qh_g, const u16* __restrict__ ql_g,
    const u16* __restrict__ kh_g, const u16* __restrict__ kl_g,
    float* __restrict__ m_i, float* __restrict__ inv_l) {
  const int n0 = blockIdx.x * 64;
  const int bk = blockIdx.y;
  const int t = threadIdx.x;
  const int w = t >> 6, lane = t & 63, l15 = lane & 15, quad = lane >> 4;
  __shared__ u16 sqh[64 * 72], sql[64 * 72], skh[64 * 72], skl[64 * 72];
  const size_t qoff = (size_t)bk * NSP * NCQ + (size_t)n0 * NCQ;
  stage64(qh_g + qoff, sqh, t);
  stage64(ql_g + qoff, sql, t);
  float runmax[4] = {-1e30f, -1e30f, -1e30f, -1e30f};
  float runsum[4] = {0.f, 0.f, 0.f, 0.f};
  const int arow = w * 16 + l15;
  for (int mt = 0; mt < 16; ++mt) {
    __syncthreads();
    const size_t koff = (size_t)bk * NSP * NCQ + (size_t)(mt * 64) * NCQ;
    stage64(kh_g + koff, skh, t);
    stage64(kl_g + koff, skl, t);
    __syncthreads();
    f32x4 e[4] = {};
    #pragma unroll
    for (int ks = 0; ks < 2; ++ks) {
      const bf16x8 ah = *(const bf16x8*)&sqh[arow * 72 + ks * 32 + quad * 8];
      const bf16x8 al = *(const bf16x8*)&sql[arow * 72 + ks * 32 + quad * 8];
      #pragma unroll
      for (int fj = 0; fj < 4; ++fj) {
        const int brow = fj * 16 + l15;
        const bf16x8 bh = *(const bf16x8*)&skh[brow * 72 + ks * 32 + quad * 8];
        const bf16x8 bl = *(const bf16x8*)&skl[brow * 72 + ks * 32 + quad * 8];
        e[fj] = __builtin_amdgcn_mfma_f32_16x16x32_bf16(ah, bh, e[fj], 0, 0, 0);
        e[fj] = __builtin_amdgcn_mfma_f32_16x16x32_bf16(ah, bl, e[fj], 0, 0, 0);
        e[fj] = __builtin_amdgcn_mfma_f32_16x16x32_bf16(al, bh, e[fj], 0, 0, 0);
      }
    }
    #pragma unroll
    for (int r = 0; r < 4; ++r) {
      float tmax = fmaxf(fmaxf(e[0][r], e[1][r]), fmaxf(e[2][r], e[3][r]));
      tmax = fmaxf(tmax, __shfl_xor(tmax, 1));
      tmax = fmaxf(tmax, __shfl_xor(tmax, 2));
      tmax = fmaxf(tmax, __shfl_xor(tmax, 4));
      tmax = fmaxf(tmax, __shfl_xor(tmax, 8));
      const float nm = fmaxf(runmax[r], tmax);
      float ts = __expf(e[0][r] - nm) + __expf(e[1][r] - nm) +
                 __expf(e[2][r] - nm) + __expf(e[3][r] - nm);
      ts += __shfl_xor(ts, 1);
      ts += __shfl_xor(ts, 2);
      ts += __shfl_xor(ts, 4);
      ts += __shfl_xor(ts, 8);
      runsum[r] = runsum[r] * __expf(runmax[r] - nm) + ts;
      runmax[r] = nm;
    }
  }
  if (l15 == 0) {
    #pragma unroll
    for (int r = 0; r < 4; ++r) {
      const int n = n0 + w * 16 + quad * 4 + r;
      m_i[(size_t)bk * NSP + n] = runmax[r];
      inv_l[(size_t)bk * NSP + n] = 1.0f / runsum[r];
    }
  }
}

// ---------------- P2b: invden[b,n,m] = 1/(1e-9 + sum_k P_k[n,m]) ------------
// grid (16 m-tiles, 16 n-tiles, NB), block 256
__global__ __launch_bounds__(256) void k_denom(
    const u16* __restrict__ qh_g, const u16* __restrict__ ql_g,
    const u16* __restrict__ kh_g, const u16* __restrict__ kl_g,
    const float* __restrict__ m_i, const float* __restrict__ inv_l,
    float* __restrict__ invden) {
  const int m0 = blockIdx.x * 64, n0 = blockIdx.y * 64, b = blockIdx.z;
  const int t = threadIdx.x;
  const int w = t >> 6, lane = t & 63, l15 = lane & 15, quad = lane >> 4;
  __shared__ u16 sqh[64 * 72], sql[64 * 72], skh[64 * 72], skl[64 * 72];
  float den[4][4] = {};  // [fj][r]
  const int arow = w * 16 + l15;
  for (int kk = 0; kk < NKK; ++kk) {
    const int bk = b * NKK + kk;
    __syncthreads();
    const size_t qoff = (size_t)bk * NSP * NCQ + (size_t)n0 * NCQ;
    const size_t koff = (size_t)bk * NSP * NCQ + (size_t)m0 * NCQ;
    stage64(qh_g + qoff, sqh, t);
    stage64(ql_g + qoff, sql, t);
    stage64(kh_g + koff, skh, t);
    stage64(kl_g + koff, skl, t);
    __syncthreads();
    f32x4 e[4] = {};
    #pragma unroll
    for (int ks = 0; ks < 2; ++ks) {
      const bf16x8 ah = *(const bf16x8*)&sqh[arow * 72 + ks * 32 + quad * 8];
      const bf16x8 al = *(const bf16x8*)&sql[arow * 72 + ks * 32 + quad * 8];
      #pragma unroll
      for (int fj = 0; fj < 4; ++fj) {
        const int brow = fj * 16 + l15;
        const bf16x8 bh = *(const bf16x8*)&skh[brow * 72 + ks * 32 + quad * 8];
        const bf16x8 bl = *(const bf16x8*)&skl[brow * 72 + ks * 32 + quad * 8];
        e[fj] = __builtin_amdgcn_mfma_f32_16x16x32_bf16(ah, bh, e[fj], 0, 0, 0);
        e[fj] = __builtin_amdgcn_mfma_f32_16x16x32_bf16(ah, bl, e[fj], 0, 0, 0);
        e[fj] = __builtin_amdgcn_mfma_f32_16x16x32_bf16(al, bh, e[fj], 0, 0, 0);
      }
    }
    float smv[4], slv[4];
    #pragma unroll
    for (int r = 0; r < 4; ++r) {
      const int n = n0 + w * 16 + quad * 4 + r;
      smv[r] = m_i[(size_t)bk * NSP + n];
      slv[r] = inv_l[(size_t)bk * NSP + n];
    }
    #pragma unroll
    for (int fj = 0; fj < 4; ++fj)
      #pragma unroll
      for (int r = 0; r < 4; ++r)
        den[fj][r] += __expf(e[fj][r] - smv[r]) * slv[r];
  }
  #pragma unroll
  for (int fj = 0; fj < 4; ++fj)
    #pragma unroll
    for (int r = 0; r < 4; ++r) {
      const int n = n0 + w * 16 + quad * 4 + r;
      invden[(size_t)b * NSP * NSP + (size_t)n * NSP + m0 + fj * 16 + l15] =
          1.0f / (1e-9f + den[fj][r]);
    }
}

// ---------------- P3: txr[bk][c][m] = sum_n u[bk][c][n] * At[n][m] ----------
// E recomputed via split-bf16 MFMA; At formed bf16 in LDS; apply via bf16 MFMA
// grid (16 m-tiles, NBK), block 256 (4 waves; E: wave w -> n rows w*16..+16;
// apply: wave w -> c rows w*64..+64)
__global__ __launch_bounds__(256) void k_xr(
    const u16* __restrict__ qh_g, const u16* __restrict__ ql_g,
    const u16* __restrict__ kh_g, const u16* __restrict__ kl_g,
    const u16* __restrict__ u_g, const float* __restrict__ m_i,
    const float* __restrict__ inv_l, const float* __restrict__ invden,
    float* __restrict__ txr) {
  const int m0 = blockIdx.x * 64;
  const int bk = blockIdx.y;
  const int b = bk >> 4;
  const int t = threadIdx.x;
  const int w = t >> 6, lane = t & 63, l15 = lane & 15, quad = lane >> 4;
  __shared__ u16 sqh[64 * 72], sql[64 * 72], skh[64 * 72], skl[64 * 72];
  __shared__ u16 sat[64 * 72];  // At [m-local][n-local]
  f32x4 acc[4][4] = {};         // [ci][fj]
  const size_t koff = (size_t)bk * NSP * NCQ + (size_t)m0 * NCQ;
  stage64(kh_g + koff, skh, t);
  stage64(kl_g + koff, skl, t);
  const float* dp = invden + (size_t)b * NSP * NSP;
  const u16* up = u_g + (size_t)bk * NCHN * NSP;
  const int arow = w * 16 + l15;
  for (int nt = 0; nt < 16; ++nt) {
    const int n0 = nt * 64;
    __syncthreads();
    const size_t qoff = (size_t)bk * NSP * NCQ + (size_t)n0 * NCQ;
    stage64(qh_g + qoff, sqh, t);
    stage64(ql_g + qoff, sql, t);
    __syncthreads();
    // E phase
    f32x4 e[4] = {};
    #pragma unroll
    for (int ks = 0; ks < 2; ++ks) {
      const bf16x8 ah = *(const bf16x8*)&sqh[arow * 72 + ks * 32 + quad * 8];
      const bf16x8 al = *(const bf16x8*)&sql[arow * 72 + ks * 32 + quad * 8];
      #pragma unroll
      for (int fj = 0; fj < 4; ++fj) {
        const int brow = fj * 16 + l15;
        const bf16x8 bh = *(const bf16x8*)&skh[brow * 72 + ks * 32 + quad * 8];
        const bf16x8 bl = *(const bf16x8*)&skl[brow * 72 + ks * 32 + quad * 8];
        e[fj] = __builtin_amdgcn_mfma_f32_16x16x32_bf16(ah, bh, e[fj], 0, 0, 0);
        e[fj] = __builtin_amdgcn_mfma_f32_16x16x32_bf16(ah, bl, e[fj], 0, 0, 0);
        e[fj] = __builtin_amdgcn_mfma_f32_16x16x32_bf16(al, bh, e[fj], 0, 0, 0);
      }
    }
    float smv[4], slv[4];
    #pragma unroll
    for (int r = 0; r < 4; ++r) {
      const int n = n0 + w * 16 + quad * 4 + r;
      smv[r] = m_i[(size_t)bk * NSP + n];
      slv[r] = inv_l[(size_t)bk * NSP + n];
    }
    #pragma unroll
    for (int fj = 0; fj < 4; ++fj) {
      const int m = m0 + fj * 16 + l15;
      float p[4];
      #pragma unroll
      for (int r = 0; r < 4; ++r) {
        const int n = n0 + w * 16 + quad * 4 + r;
        p[r] = __expf(e[fj][r] - smv[r]) * slv[r] * dp[(size_t)n * NSP + m];
      }
      ushort4 pk;
      pk.x = f2bf(p[0]); pk.y = f2bf(p[1]); pk.z = f2bf(p[2]); pk.w = f2bf(p[3]);
      *reinterpret_cast<ushort4*>(&sat[(fj * 16 + l15) * 72 + w * 16 + quad * 4]) = pk;
    }
    __syncthreads();
    // apply phase
    #pragma unroll
    for (int ks = 0; ks < 2; ++ks) {
      bf16x8 bfr[4];
      #pragma unroll
      for (int fj = 0; fj < 4; ++fj)
        bfr[fj] = *(const bf16x8*)&sat[(fj * 16 + l15) * 72 + ks * 32 + quad * 8];
      #pragma unroll
      for (int ci = 0; ci < 4; ++ci) {
        const int c = w * 64 + ci * 16 + l15;
        const bf16x8 a =
            *reinterpret_cast<const bf16x8*>(up + (size_t)c * NSP + n0 + ks * 32 + quad * 8);
        #pragma unroll
        for (int fj = 0; fj < 4; ++fj)
          acc[ci][fj] = __builtin_amdgcn_mfma_f32_16x16x32_bf16(a, bfr[fj], acc[ci][fj], 0, 0, 0);
      }
    }
  }
  #pragma unroll
  for (int ci = 0; ci < 4; ++ci)
    #pragma unroll
    for (int fj = 0; fj < 4; ++fj)
      #pragma unroll
      for (int r = 0; r < 4; ++r) {
        const int c = w * 64 + ci * 16 + quad * 4 + r;
        const int m = m0 + fj * 16 + l15;
        txr[((size_t)bk * NCHN + c) * NSP + m] = acc[ci][fj][r];
      }
}

// ---------------- P4a: BN partial sums over t = s + t_b - TxR ----------------
__global__ __launch_bounds__(256) void k_bnstats(
    const bf16* __restrict__ s, const float* __restrict__ txr,
    const float* __restrict__ t_b, float* __restrict__ bnsum,
    float* __restrict__ bnsq) {
  const int c = blockIdx.x, b = blockIdx.y, t = threadIdx.x;
  __shared__ float tx[16 * 273];
  __shared__ float r1[256], r2[256];
  const bf16* sp = s + ((size_t)b * NCHN + c) * NPK;
  const float tb = t_b[c];
  float lsum = 0.f, lss = 0.f;
  for (int n0 = 0; n0 < NSP; n0 += 256) {
    for (int idx = t; idx < 4096; idx += 256) {
      const int kk = idx >> 8, nn = idx & 255;
      tx[kk * 273 + nn] = txr[(((size_t)b * NKK + kk) * NCHN + c) * NSP + n0 + nn];
    }
    __syncthreads();
    for (int idx = t; idx < 4096; idx += 256) {
      const int nn = idx >> 4, kk = idx & 15;
      const float tv = bf2f(sp[n0 * NKK + idx]) + tb - tx[kk * 273 + nn];
      lsum += tv;
      lss = fmaf(tv, tv, lss);
    }
    __syncthreads();
  }
  r1[t] = lsum; r2[t] = lss;
  __syncthreads();
  for (int sh = 128; sh > 0; sh >>= 1) {
    if (t < sh) { r1[t] += r1[t + sh]; r2[t] += r2[t + sh]; }
    __syncthreads();
  }
  if (t == 0) {
    atomicAdd(&bnsum[c], r1[0]);
    atomicAdd(&bnsq[c], r2[0]);
  }
}

// ---------------- P4b: finalize BN affine ----------------
__global__ void k_bnfin(const float* __restrict__ bnsum, const float* __restrict__ bnsq,
                        const float* __restrict__ gamma, const float* __restrict__ beta,
                        float* __restrict__ abuf, float* __restrict__ bbuf) {
  const int c = threadIdx.x;
  const float inv_m = 1.0f / 131072.0f;
  const float mean = bnsum[c] * inv_m;
  const float var = bnsq[c] * inv_m - mean * mean;
  const float a = gamma[c] * rsqrtf(var + 1e-5f);
  abuf[c] = a;
  bbuf[c] = beta[c] - mean * a;
}

// ---------------- P4c: out = x + relu(a*t + bb) ----------------
__global__ __launch_bounds__(256) void k_out(
    const float* __restrict__ x, const bf16* __restrict__ s,
    const float* __restrict__ txr, const float* __restrict__ t_b,
    const float* __restrict__ abuf, const float* __restrict__ bbuf,
    float* __restrict__ out) {
  const int c = blockIdx.x, b = blockIdx.y, t = threadIdx.x;
  __shared__ float tx[16 * 273];
  const bf16* sp = s + ((size_t)b * NCHN + c) * NPK;
  const float* xp = x + ((size_t)b * NCHN + c) * NPK;
  float* op = out + ((size_t)b * NCHN + c) * NPK;
  const float tb = t_b[c], a = abuf[c], bb = bbuf[c];
  for (int n0 = 0; n0 < NSP; n0 += 256) {
    for (int idx = t; idx < 4096; idx += 256) {
      const int kk = idx >> 8, nn = idx & 255;
      tx[kk * 273 + nn] = txr[(((size_t)b * NKK + kk) * NCHN + c) * NSP + n0 + nn];
    }
    __syncthreads();
    for (int idx = t; idx < 4096; idx += 256) {
      const int nn = idx >> 4, kk = idx & 15;
      const float tv = bf2f(sp[n0 * NKK + idx]) + tb - tx[kk * 273 + nn];
      const float r = fmaxf(fmaf(tv, a, bb), 0.f);
      op[n0 * NKK + idx] = xp[n0 * NKK + idx] + r;
    }
    __syncthreads();
  }
}

extern "C" void kernel_launch(void* const* d_in, const int* in_sizes, int n_in,
                              void* d_out, int out_size, void* d_ws, size_t ws_size,
                              hipStream_t stream) {
  (void)in_sizes; (void)n_in; (void)out_size; (void)ws_size;
  const float* x     = (const float*)d_in[0];
  const float* q_w   = (const float*)d_in[1];
  const float* k_w   = (const float*)d_in[2];
  const float* v_w   = (const float*)d_in[3];
  const float* v_b   = (const float*)d_in[4];
  const float* t_w   = (const float*)d_in[5];
  const float* t_b   = (const float*)d_in[6];
  const float* gamma = (const float*)d_in[7];
  const float* beta  = (const float*)d_in[8];
  float* out = (float*)d_out;

  // workspace carve (bytes)
  char* w = (char*)d_ws;
  float* invden = (float*)w; w += (size_t)NB * NSP * NSP * 4;      // 33.5 MB
  float* txr    = (float*)w; w += (size_t)NBK * NCHN * NSP * 4;    // 134 MB
  u16*   qh     = (u16*)w;   w += (size_t)NBK * NSP * NCQ * 2;     // 16.8 MB
  u16*   ql     = (u16*)w;   w += (size_t)NBK * NSP * NCQ * 2;
  u16*   kh     = (u16*)w;   w += (size_t)NBK * NSP * NCQ * 2;
  u16*   kl     = (u16*)w;   w += (size_t)NBK * NSP * NCQ * 2;
  bf16*  u      = (bf16*)w;  w += (size_t)NBK * NCHN * NSP * 2;    // 67 MB
  bf16*  s      = (bf16*)w;  w += (size_t)NB * NCHN * NPK * 2;     // 67 MB
  float* m_i    = (float*)w; w += (size_t)NBK * NSP * 4;
  float* inv_l  = (float*)w; w += (size_t)NBK * NSP * 4;
  float* w2     = (float*)w; w += (size_t)NCHN * NCHN * 4;
  float* ub     = (float*)w; w += 1024;
  float* bnsum  = (float*)w; w += 1024;
  float* bnsq   = (float*)w; w += 1024;
  float* abuf   = (float*)w; w += 1024;
  float* bbuf   = (float*)w; w += 1024;

  k_zero<<<dim3(2), dim3(256), 0, stream>>>(bnsum, 512);  // bnsum + bnsq
  k_w2<<<dim3(256), dim3(256), 0, stream>>>(t_w, v_w, v_b, w2, ub);
  k_proj<<<dim3(NPK / 64, 10, NB), dim3(256), 0, stream>>>(
      x, q_w, k_w, w2, t_w, ub, qh, ql, kh, kl, u, s);
  k_stats<<<dim3(16, NBK), dim3(256), 0, stream>>>(qh, ql, kh, kl, m_i, inv_l);
  k_denom<<<dim3(16, 16, NB), dim3(256), 0, stream>>>(qh, ql, kh, kl, m_i, inv_l, invden);
  k_xr<<<dim3(16, NBK), dim3(256), 0, stream>>>(qh, ql, kh, kl, (const u16*)u, m_i,
                                                inv_l, invden, txr);
  k_bnstats<<<dim3(NCHN, NB), dim3(256), 0, stream>>>(s, txr, t_b, bnsum, bnsq);
  k_bnfin<<<dim3(1), dim3(256), 0, stream>>>(bnsum, bnsq, gamma, beta, abuf, bbuf);
  k_out<<<dim3(NCHN, NB), dim3(256), 0, stream>>>(x, s, txr, t_b, abuf, bbuf, out);
}

// Round 3
// 1330.175 us; speedup vs baseline: 2.7370x; 1.2780x over previous
//
#include <hip/hip_runtime.h>
#include <hip/hip_bf16.h>
#include <cstdint>
#include <cstddef>

// Problem constants
#define NB   8      // batch
#define NCHN 256    // C
#define NSP  1024   // N (spatial)
#define NKK  16     // K (neighbourhood)
#define NCQ  64     // C/4
#define NPK  16384  // NSP*NKK pixels per (b)
#define NBK  128    // NB*NKK planes

typedef __hip_bfloat16 bf16;
typedef unsigned short u16;
typedef __attribute__((ext_vector_type(8))) short bf16x8;
typedef __attribute__((ext_vector_type(4))) float f32x4;

__device__ __forceinline__ float bf2f(bf16 v) { return __bfloat162float(v); }

// raw bf16 (RNE) from float, and back
__device__ __forceinline__ u16 f2bf(float x) {
  unsigned b = __float_as_uint(x);
  return (u16)((b + 0x7FFF + ((b >> 16) & 1)) >> 16);
}
__device__ __forceinline__ float bfr2f(u16 u) { return __uint_as_float(((unsigned)u) << 16); }
__device__ __forceinline__ float bfr2f_s(u16 u) { return bfr2f(u); }

// stage a contiguous [64 rows][64 u16] global tile into LDS [64][72] (pad 16B)
__device__ __forceinline__ void stage64(const u16* __restrict__ g, u16* __restrict__ l, int t) {
  #pragma unroll
  for (int i = 0; i < 2; ++i) {
    const int idx = t + i * 256;
    const int row = idx >> 3, col = (idx & 7) * 8;
    const bf16x8 v = *reinterpret_cast<const bf16x8*>(g + (size_t)row * 64 + col);
    *reinterpret_cast<bf16x8*>(l + row * 72 + col) = v;
  }
}

// ---------------- P0a: W2 = t_w @ v_w, ub = t_w @ v_b ----------------
__global__ __launch_bounds__(256) void k_w2(const float* __restrict__ t_w,
                                            const float* __restrict__ v_w,
                                            const float* __restrict__ v_b,
                                            float* __restrict__ w2,
                                            float* __restrict__ ub) {
  const int o = blockIdx.x;   // 0..255
  const int c = threadIdx.x;  // 0..255
  __shared__ float trow[NCHN];
  __shared__ float red[NCHN];
  trow[c] = t_w[o * NCHN + c];
  __syncthreads();
  float acc = 0.f;
  for (int m = 0; m < NCHN; ++m) acc = fmaf(trow[m], v_w[m * NCHN + c], acc);
  w2[o * NCHN + c] = acc;
  red[c] = trow[c] * v_b[c];
  __syncthreads();
  for (int s = 128; s > 0; s >>= 1) {
    if (c < s) red[c] += red[c + s];
    __syncthreads();
  }
  if (c == 0) ub[o] = red[0];
}

// ---------------- P0b: split all weights into bf16 hi/lo [640][256] --------
// o<64: q_w; o<128: k_w; o<384: w2; o<640: t_w
__global__ __launch_bounds__(256) void k_wsplit(
    const float* __restrict__ q_w, const float* __restrict__ k_w,
    const float* __restrict__ w2, const float* __restrict__ t_w,
    u16* __restrict__ wh, u16* __restrict__ wl) {
  const int o = blockIdx.x, c = threadIdx.x;
  float v;
  if (o < 64)       v = q_w[o * NCHN + c];
  else if (o < 128) v = k_w[(o - 64) * NCHN + c];
  else if (o < 384) v = w2[(o - 128) * NCHN + c];
  else              v = t_w[(o - 384) * NCHN + c];
  const u16 hi = f2bf(v);
  wh[o * NCHN + c] = hi;
  wl[o * NCHN + c] = f2bf(v - bfr2f(hi));
}

// ---------------- P0c: xT[b][p][c] split bf16 hi/lo (transpose of x) -------
// grid (4 c-tiles, 256 p-tiles, NB), block 256
__global__ __launch_bounds__(256) void k_xsplit(
    const float* __restrict__ x, u16* __restrict__ xh, u16* __restrict__ xl) {
  const int c0 = blockIdx.x * 64, p0 = blockIdx.y * 64, b = blockIdx.z;
  const int t = threadIdx.x;
  __shared__ float tile[64][65];
  const float* xb = x + ((size_t)b * NCHN + c0) * NPK + p0;
  #pragma unroll
  for (int it = 0; it < 4; ++it) {
    const int item = t + it * 256;
    const int row = item >> 4, colg = item & 15;
    const float4 v = *reinterpret_cast<const float4*>(xb + (size_t)row * NPK + colg * 4);
    tile[row][colg * 4 + 0] = v.x;
    tile[row][colg * 4 + 1] = v.y;
    tile[row][colg * 4 + 2] = v.z;
    tile[row][colg * 4 + 3] = v.w;
  }
  __syncthreads();
  #pragma unroll
  for (int it = 0; it < 2; ++it) {
    const int item = t + it * 256;
    const int pl = item >> 3, cg = item & 7;
    u16 hi[8], lo[8];
    #pragma unroll
    for (int jj = 0; jj < 8; ++jj) {
      const float v = tile[cg * 8 + jj][pl];
      hi[jj] = f2bf(v);
      lo[jj] = f2bf(v - bfr2f(hi[jj]));
    }
    const size_t base = ((size_t)b * NPK + p0 + pl) * NCHN + c0 + cg * 8;
    *reinterpret_cast<bf16x8*>(xh + base) = *reinterpret_cast<const bf16x8*>(hi);
    *reinterpret_cast<bf16x8*>(xl + base) = *reinterpret_cast<const bf16x8*>(lo);
  }
}

// ---------------- zero helper ----------------
__global__ void k_zero(float* __restrict__ p, int n) {
  int i = blockIdx.x * 256 + threadIdx.x;
  if (i < n) p[i] = 0.f;
}

// ---------------- P1: MFMA projection ----------------
// Block computes 320 o-channels x 64 pixels; no LDS, no barriers.
// o<64: q -> qh/ql[bk][n][d] (3-product split); o<128: k -> kh/kl;
// o<384: u[bk][c][n] (+ub, bf16, 1-product); o<640: s[b][c][p] (bf16)
// grid (2 o-halves, 256 p-tiles, NB), block 256
__global__ __launch_bounds__(256) void k_projm(
    const u16* __restrict__ xh, const u16* __restrict__ xl,
    const u16* __restrict__ wh, const u16* __restrict__ wl,
    const float* __restrict__ ub,
    u16* __restrict__ qh, u16* __restrict__ ql,
    u16* __restrict__ kh, u16* __restrict__ kl,
    bf16* __restrict__ u, bf16* __restrict__ s) {
  const int oh = blockIdx.x;
  const int p0 = blockIdx.y * 64;
  const int b  = blockIdx.z;
  const int t = threadIdx.x, w = t >> 6, lane = t & 63, l15 = lane & 15, quad = lane >> 4;
  const int obase = oh * 320 + w * 80;
  const bool anyqk = obase < 128;
  f32x4 acc[5][4] = {};
  const u16* xhb = xh + ((size_t)b * NPK + p0) * NCHN;
  const u16* xlb = xl + ((size_t)b * NPK + p0) * NCHN;
  for (int kc = 0; kc < 8; ++kc) {
    const int c0 = kc * 32 + quad * 8;
    bf16x8 bhf[4], blf[4];
    #pragma unroll
    for (int fj = 0; fj < 4; ++fj) {
      const size_t roff = (size_t)(fj * 16 + l15) * NCHN + c0;
      bhf[fj] = *reinterpret_cast<const bf16x8*>(xhb + roff);
      if (anyqk) blf[fj] = *reinterpret_cast<const bf16x8*>(xlb + roff);
    }
    #pragma unroll
    for (int fi = 0; fi < 5; ++fi) {
      const int orow = obase + fi * 16;
      const size_t aoff = (size_t)(orow + l15) * NCHN + c0;
      const bf16x8 ah = *reinterpret_cast<const bf16x8*>(wh + aoff);
      if (orow < 128) {
        const bf16x8 al = *reinterpret_cast<const bf16x8*>(wl + aoff);
        #pragma unroll
        for (int fj = 0; fj < 4; ++fj) {
          acc[fi][fj] = __builtin_amdgcn_mfma_f32_16x16x32_bf16(ah, bhf[fj], acc[fi][fj], 0, 0, 0);
          acc[fi][fj] = __builtin_amdgcn_mfma_f32_16x16x32_bf16(ah, blf[fj], acc[fi][fj], 0, 0, 0);
          acc[fi][fj] = __builtin_amdgcn_mfma_f32_16x16x32_bf16(al, bhf[fj], acc[fi][fj], 0, 0, 0);
        }
      } else {
        #pragma unroll
        for (int fj = 0; fj < 4; ++fj)
          acc[fi][fj] = __builtin_amdgcn_mfma_f32_16x16x32_bf16(ah, bhf[fj], acc[fi][fj], 0, 0, 0);
      }
    }
  }
  // epilogue: scatter by destination layout
  #pragma unroll
  for (int fi = 0; fi < 5; ++fi)
    #pragma unroll
    for (int fj = 0; fj < 4; ++fj)
      #pragma unroll
      for (int r = 0; r < 4; ++r) {
        const int o = obase + fi * 16 + quad * 4 + r;
        const int p = p0 + fj * 16 + l15;
        const int n = p >> 4, kk = p & 15;
        const float v = acc[fi][fj][r];
        if (o < 64) {
          const size_t base = (((size_t)b * NKK + kk) * NSP + n) * NCQ + o;
          const u16 hi = f2bf(v);
          qh[base] = hi;
          ql[base] = f2bf(v - bfr2f(hi));
        } else if (o < 128) {
          const size_t base = (((size_t)b * NKK + kk) * NSP + n) * NCQ + (o - 64);
          const u16 hi = f2bf(v);
          kh[base] = hi;
          kl[base] = f2bf(v - bfr2f(hi));
        } else if (o < 384) {
          const int c = o - 128;
          u[(((size_t)b * NKK + kk) * NCHN + c) * NSP + n] = __float2bfloat16(v + ub[c]);
        } else {
          const int c = o - 384;
          s[((size_t)b * NCHN + c) * NPK + p] = __float2bfloat16(v);
        }
      }
}

// ---------------- P2a: softmax row stats via split-bf16 MFMA ----------------
// grid (16 n-tiles, NBK), block 256 (4 waves; wave w -> n rows w*16..w*16+16)
__global__ __launch_bounds__(256) void k_stats(
    const u16* __restrict__ qh_g, const u16* __restrict__ ql_g,
    const u16* __restrict__ kh_g, const u16* __restrict__ kl_g,
    float* __restrict__ m_i, float* __restrict__ inv_l) {
  const int n0 = blockIdx.x * 64;
  const int bk = blockIdx.y;
  const int t = threadIdx.x;
  const int w = t >> 6, lane = t & 63, l15 = lane & 15, quad = lane >> 4;
  __shared__ u16 sqh[64 * 72], sql[64 * 72], skh[64 * 72], skl[64 * 72];
  const size_t qoff = (size_t)bk * NSP * NCQ + (size_t)n0 * NCQ;
  stage64(qh_g + qoff, sqh, t);
  stage64(ql_g + qoff, sql, t);
  float runmax[4] = {-1e30f, -1e30f, -1e30f, -1e30f};
  float runsum[4] = {0.f, 0.f, 0.f, 0.f};
  const int arow = w * 16 + l15;
  for (int mt = 0; mt < 16; ++mt) {
    __syncthreads();
    const size_t koff = (size_t)bk * NSP * NCQ + (size_t)(mt * 64) * NCQ;
    stage64(kh_g + koff, skh, t);
    stage64(kl_g + koff, skl, t);
    __syncthreads();
    f32x4 e[4] = {};
    #pragma unroll
    for (int ks = 0; ks < 2; ++ks) {
      const bf16x8 ah = *(const bf16x8*)&sqh[arow * 72 + ks * 32 + quad * 8];
      const bf16x8 al = *(const bf16x8*)&sql[arow * 72 + ks * 32 + quad * 8];
      #pragma unroll
      for (int fj = 0; fj < 4; ++fj) {
        const int brow = fj * 16 + l15;
        const bf16x8 bh = *(const bf16x8*)&skh[brow * 72 + ks * 32 + quad * 8];
        const bf16x8 bl = *(const bf16x8*)&skl[brow * 72 + ks * 32 + quad * 8];
        e[fj] = __builtin_amdgcn_mfma_f32_16x16x32_bf16(ah, bh, e[fj], 0, 0, 0);
        e[fj] = __builtin_amdgcn_mfma_f32_16x16x32_bf16(ah, bl, e[fj], 0, 0, 0);
        e[fj] = __builtin_amdgcn_mfma_f32_16x16x32_bf16(al, bh, e[fj], 0, 0, 0);
      }
    }
    #pragma unroll
    for (int r = 0; r < 4; ++r) {
      float tmax = fmaxf(fmaxf(e[0][r], e[1][r]), fmaxf(e[2][r], e[3][r]));
      tmax = fmaxf(tmax, __shfl_xor(tmax, 1));
      tmax = fmaxf(tmax, __shfl_xor(tmax, 2));
      tmax = fmaxf(tmax, __shfl_xor(tmax, 4));
      tmax = fmaxf(tmax, __shfl_xor(tmax, 8));
      const float nm = fmaxf(runmax[r], tmax);
      float ts = __expf(e[0][r] - nm) + __expf(e[1][r] - nm) +
                 __expf(e[2][r] - nm) + __expf(e[3][r] - nm);
      ts += __shfl_xor(ts, 1);
      ts += __shfl_xor(ts, 2);
      ts += __shfl_xor(ts, 4);
      ts += __shfl_xor(ts, 8);
      runsum[r] = runsum[r] * __expf(runmax[r] - nm) + ts;
      runmax[r] = nm;
    }
  }
  if (l15 == 0) {
    #pragma unroll
    for (int r = 0; r < 4; ++r) {
      const int n = n0 + w * 16 + quad * 4 + r;
      m_i[(size_t)bk * NSP + n] = runmax[r];
      inv_l[(size_t)bk * NSP + n] = 1.0f / runsum[r];
    }
  }
}

// ---------------- P2b: invden[b,n,m] = 1/(1e-9 + sum_k P_k[n,m]) ------------
// grid (16 m-tiles, 16 n-tiles, NB), block 256
__global__ __launch_bounds__(256) void k_denom(
    const u16* __restrict__ qh_g, const u16* __restrict__ ql_g,
    const u16* __restrict__ kh_g, const u16* __restrict__ kl_g,
    const float* __restrict__ m_i, const float* __restrict__ inv_l,
    float* __restrict__ invden) {
  const int m0 = blockIdx.x * 64, n0 = blockIdx.y * 64, b = blockIdx.z;
  const int t = threadIdx.x;
  const int w = t >> 6, lane = t & 63, l15 = lane & 15, quad = lane >> 4;
  __shared__ u16 sqh[64 * 72], sql[64 * 72], skh[64 * 72], skl[64 * 72];
  float den[4][4] = {};  // [fj][r]
  const int arow = w * 16 + l15;
  for (int kk = 0; kk < NKK; ++kk) {
    const int bk = b * NKK + kk;
    __syncthreads();
    const size_t qoff = (size_t)bk * NSP * NCQ + (size_t)n0 * NCQ;
    const size_t koff = (size_t)bk * NSP * NCQ + (size_t)m0 * NCQ;
    stage64(qh_g + qoff, sqh, t);
    stage64(ql_g + qoff, sql, t);
    stage64(kh_g + koff, skh, t);
    stage64(kl_g + koff, skl, t);
    __syncthreads();
    f32x4 e[4] = {};
    #pragma unroll
    for (int ks = 0; ks < 2; ++ks) {
      const bf16x8 ah = *(const bf16x8*)&sqh[arow * 72 + ks * 32 + quad * 8];
      const bf16x8 al = *(const bf16x8*)&sql[arow * 72 + ks * 32 + quad * 8];
      #pragma unroll
      for (int fj = 0; fj < 4; ++fj) {
        const int brow = fj * 16 + l15;
        const bf16x8 bh = *(const bf16x8*)&skh[brow * 72 + ks * 32 + quad * 8];
        const bf16x8 bl = *(const bf16x8*)&skl[brow * 72 + ks * 32 + quad * 8];
        e[fj] = __builtin_amdgcn_mfma_f32_16x16x32_bf16(ah, bh, e[fj], 0, 0, 0);
        e[fj] = __builtin_amdgcn_mfma_f32_16x16x32_bf16(ah, bl, e[fj], 0, 0, 0);
        e[fj] = __builtin_amdgcn_mfma_f32_16x16x32_bf16(al, bh, e[fj], 0, 0, 0);
      }
    }
    float smv[4], slv[4];
    #pragma unroll
    for (int r = 0; r < 4; ++r) {
      const int n = n0 + w * 16 + quad * 4 + r;
      smv[r] = m_i[(size_t)bk * NSP + n];
      slv[r] = inv_l[(size_t)bk * NSP + n];
    }
    #pragma unroll
    for (int fj = 0; fj < 4; ++fj)
      #pragma unroll
      for (int r = 0; r < 4; ++r)
        den[fj][r] += __expf(e[fj][r] - smv[r]) * slv[r];
  }
  #pragma unroll
  for (int fj = 0; fj < 4; ++fj)
    #pragma unroll
    for (int r = 0; r < 4; ++r) {
      const int n = n0 + w * 16 + quad * 4 + r;
      invden[(size_t)b * NSP * NSP + (size_t)n * NSP + m0 + fj * 16 + l15] =
          1.0f / (1e-9f + den[fj][r]);
    }
}

// ---------------- P3: txr[bk][c][m] = sum_n u[bk][c][n] * At[n][m] ----------
// grid (16 m-tiles, NBK), block 256
__global__ __launch_bounds__(256) void k_xr(
    const u16* __restrict__ qh_g, const u16* __restrict__ ql_g,
    const u16* __restrict__ kh_g, const u16* __restrict__ kl_g,
    const u16* __restrict__ u_g, const float* __restrict__ m_i,
    const float* __restrict__ inv_l, const float* __restrict__ invden,
    u16* __restrict__ txr) {
  const int m0 = blockIdx.x * 64;
  const int bk = blockIdx.y;
  const int b = bk >> 4;
  const int t = threadIdx.x;
  const int w = t >> 6, lane = t & 63, l15 = lane & 15, quad = lane >> 4;
  __shared__ u16 sqh[64 * 72], sql[64 * 72], skh[64 * 72], skl[64 * 72];
  __shared__ u16 sat[64 * 72];  // At [m-local][n-local]
  f32x4 acc[4][4] = {};         // [ci][fj]
  const size_t koff = (size_t)bk * NSP * NCQ + (size_t)m0 * NCQ;
  stage64(kh_g + koff, skh, t);
  stage64(kl_g + koff, skl, t);
  const float* dp = invden + (size_t)b * NSP * NSP;
  const u16* up = u_g + (size_t)bk * NCHN * NSP;
  const int arow = w * 16 + l15;
  for (int nt = 0; nt < 16; ++nt) {
    const int n0 = nt * 64;
    __syncthreads();
    const size_t qoff = (size_t)bk * NSP * NCQ + (size_t)n0 * NCQ;
    stage64(qh_g + qoff, sqh, t);
    stage64(ql_g + qoff, sql, t);
    __syncthreads();
    // E phase
    f32x4 e[4] = {};
    #pragma unroll
    for (int ks = 0; ks < 2; ++ks) {
      const bf16x8 ah = *(const bf16x8*)&sqh[arow * 72 + ks * 32 + quad * 8];
      const bf16x8 al = *(const bf16x8*)&sql[arow * 72 + ks * 32 + quad * 8];
      #pragma unroll
      for (int fj = 0; fj < 4; ++fj) {
        const int brow = fj * 16 + l15;
        const bf16x8 bh = *(const bf16x8*)&skh[brow * 72 + ks * 32 + quad * 8];
        const bf16x8 bl = *(const bf16x8*)&skl[brow * 72 + ks * 32 + quad * 8];
        e[fj] = __builtin_amdgcn_mfma_f32_16x16x32_bf16(ah, bh, e[fj], 0, 0, 0);
        e[fj] = __builtin_amdgcn_mfma_f32_16x16x32_bf16(ah, bl, e[fj], 0, 0, 0);
        e[fj] = __builtin_amdgcn_mfma_f32_16x16x32_bf16(al, bh, e[fj], 0, 0, 0);
      }
    }
    float smv[4], slv[4];
    #pragma unroll
    for (int r = 0; r < 4; ++r) {
      const int n = n0 + w * 16 + quad * 4 + r;
      smv[r] = m_i[(size_t)bk * NSP + n];
      slv[r] = inv_l[(size_t)bk * NSP + n];
    }
    #pragma unroll
    for (int fj = 0; fj < 4; ++fj) {
      const int m = m0 + fj * 16 + l15;
      float p[4];
      #pragma unroll
      for (int r = 0; r < 4; ++r) {
        const int n = n0 + w * 16 + quad * 4 + r;
        p[r] = __expf(e[fj][r] - smv[r]) * slv[r] * dp[(size_t)n * NSP + m];
      }
      ushort4 pk;
      pk.x = f2bf(p[0]); pk.y = f2bf(p[1]); pk.z = f2bf(p[2]); pk.w = f2bf(p[3]);
      *reinterpret_cast<ushort4*>(&sat[(fj * 16 + l15) * 72 + w * 16 + quad * 4]) = pk;
    }
    __syncthreads();
    // apply phase
    #pragma unroll
    for (int ks = 0; ks < 2; ++ks) {
      bf16x8 bfr[4];
      #pragma unroll
      for (int fj = 0; fj < 4; ++fj)
        bfr[fj] = *(const bf16x8*)&sat[(fj * 16 + l15) * 72 + ks * 32 + quad * 8];
      #pragma unroll
      for (int ci = 0; ci < 4; ++ci) {
        const int c = w * 64 + ci * 16 + l15;
        const bf16x8 a =
            *reinterpret_cast<const bf16x8*>(up + (size_t)c * NSP + n0 + ks * 32 + quad * 8);
        #pragma unroll
        for (int fj = 0; fj < 4; ++fj)
          acc[ci][fj] = __builtin_amdgcn_mfma_f32_16x16x32_bf16(a, bfr[fj], acc[ci][fj], 0, 0, 0);
      }
    }
  }
  #pragma unroll
  for (int ci = 0; ci < 4; ++ci)
    #pragma unroll
    for (int fj = 0; fj < 4; ++fj)
      #pragma unroll
      for (int r = 0; r < 4; ++r) {
        const int c = w * 64 + ci * 16 + quad * 4 + r;
        const int m = m0 + fj * 16 + l15;
        txr[((size_t)bk * NCHN + c) * NSP + m] = f2bf(acc[ci][fj][r]);
      }
}

// ---------------- P4a: BN partial sums over t = s + t_b - TxR ----------------
__global__ __launch_bounds__(256) void k_bnstats(
    const bf16* __restrict__ s, const u16* __restrict__ txr,
    const float* __restrict__ t_b, float* __restrict__ bnsum,
    float* __restrict__ bnsq) {
  const int c = blockIdx.x, b = blockIdx.y, t = threadIdx.x;
  __shared__ float tx[16 * 273];
  __shared__ float r1[256], r2[256];
  const bf16* sp = s + ((size_t)b * NCHN + c) * NPK;
  const float tb = t_b[c];
  float lsum = 0.f, lss = 0.f;
  for (int n0 = 0; n0 < NSP; n0 += 256) {
    for (int idx = t; idx < 4096; idx += 256) {
      const int kk = idx >> 8, nn = idx & 255;
      tx[kk * 273 + nn] = bfr2f_s(txr[(((size_t)b * NKK + kk) * NCHN + c) * NSP + n0 + nn]);
    }
    __syncthreads();
    for (int idx = t; idx < 4096; idx += 256) {
      const int nn = idx >> 4, kk = idx & 15;
      const float tv = bf2f(sp[n0 * NKK + idx]) + tb - tx[kk * 273 + nn];
      lsum += tv;
      lss = fmaf(tv, tv, lss);
    }
    __syncthreads();
  }
  r1[t] = lsum; r2[t] = lss;
  __syncthreads();
  for (int sh = 128; sh > 0; sh >>= 1) {
    if (t < sh) { r1[t] += r1[t + sh]; r2[t] += r2[t + sh]; }
    __syncthreads();
  }
  if (t == 0) {
    atomicAdd(&bnsum[c], r1[0]);
    atomicAdd(&bnsq[c], r2[0]);
  }
}

// ---------------- P4b: finalize BN affine ----------------
__global__ void k_bnfin(const float* __restrict__ bnsum, const float* __restrict__ bnsq,
                        const float* __restrict__ gamma, const float* __restrict__ beta,
                        float* __restrict__ abuf, float* __restrict__ bbuf) {
  const int c = threadIdx.x;
  const float inv_m = 1.0f / 131072.0f;
  const float mean = bnsum[c] * inv_m;
  const float var = bnsq[c] * inv_m - mean * mean;
  const float a = gamma[c] * rsqrtf(var + 1e-5f);
  abuf[c] = a;
  bbuf[c] = beta[c] - mean * a;
}

// ---------------- P4c: out = x + relu(a*t + bb) ----------------
__global__ __launch_bounds__(256) void k_out(
    const float* __restrict__ x, const bf16* __restrict__ s,
    const u16* __restrict__ txr, const float* __restrict__ t_b,
    const float* __restrict__ abuf, const float* __restrict__ bbuf,
    float* __restrict__ out) {
  const int c = blockIdx.x, b = blockIdx.y, t = threadIdx.x;
  __shared__ float tx[16 * 273];
  const bf16* sp = s + ((size_t)b * NCHN + c) * NPK;
  const float* xp = x + ((size_t)b * NCHN + c) * NPK;
  float* op = out + ((size_t)b * NCHN + c) * NPK;
  const float tb = t_b[c], a = abuf[c], bb = bbuf[c];
  for (int n0 = 0; n0 < NSP; n0 += 256) {
    for (int idx = t; idx < 4096; idx += 256) {
      const int kk = idx >> 8, nn = idx & 255;
      tx[kk * 273 + nn] = bfr2f_s(txr[(((size_t)b * NKK + kk) * NCHN + c) * NSP + n0 + nn]);
    }
    __syncthreads();
    for (int idx = t; idx < 4096; idx += 256) {
      const int nn = idx >> 4, kk = idx & 15;
      const float tv = bf2f(sp[n0 * NKK + idx]) + tb - tx[kk * 273 + nn];
      const float r = fmaxf(fmaf(tv, a, bb), 0.f);
      op[n0 * NKK + idx] = xp[n0 * NKK + idx] + r;
    }
    __syncthreads();
  }
}

extern "C" void kernel_launch(void* const* d_in, const int* in_sizes, int n_in,
                              void* d_out, int out_size, void* d_ws, size_t ws_size,
                              hipStream_t stream) {
  (void)in_sizes; (void)n_in; (void)out_size; (void)ws_size;
  const float* x     = (const float*)d_in[0];
  const float* q_w   = (const float*)d_in[1];
  const float* k_w   = (const float*)d_in[2];
  const float* v_w   = (const float*)d_in[3];
  const float* v_b   = (const float*)d_in[4];
  const float* t_w   = (const float*)d_in[5];
  const float* t_b   = (const float*)d_in[6];
  const float* gamma = (const float*)d_in[7];
  const float* beta  = (const float*)d_in[8];
  float* out = (float*)d_out;

  // workspace carve (bytes)
  char* w = (char*)d_ws;
  float* invden = (float*)w; w += (size_t)NB * NSP * NSP * 4;      // 33.5 MB
  u16*   txr    = (u16*)w;   w += (size_t)NBK * NCHN * NSP * 2;    // 67 MB
  u16*   qh     = (u16*)w;   w += (size_t)NBK * NSP * NCQ * 2;     // 16.8 MB
  u16*   ql     = (u16*)w;   w += (size_t)NBK * NSP * NCQ * 2;
  u16*   kh     = (u16*)w;   w += (size_t)NBK * NSP * NCQ * 2;
  u16*   kl     = (u16*)w;   w += (size_t)NBK * NSP * NCQ * 2;
  bf16*  u      = (bf16*)w;  w += (size_t)NBK * NCHN * NSP * 2;    // 67 MB
  bf16*  s      = (bf16*)w;  w += (size_t)NB * NCHN * NPK * 2;     // 67 MB
  u16*   xh     = (u16*)w;   w += (size_t)NB * NPK * NCHN * 2;     // 67 MB
  u16*   xl     = (u16*)w;   w += (size_t)NB * NPK * NCHN * 2;     // 67 MB
  u16*   whb    = (u16*)w;   w += (size_t)640 * NCHN * 2;
  u16*   wlb    = (u16*)w;   w += (size_t)640 * NCHN * 2;
  float* m_i    = (float*)w; w += (size_t)NBK * NSP * 4;
  float* inv_l  = (float*)w; w += (size_t)NBK * NSP * 4;
  float* w2     = (float*)w; w += (size_t)NCHN * NCHN * 4;
  float* ub     = (float*)w; w += 1024;
  float* bnsum  = (float*)w; w += 1024;
  float* bnsq   = (float*)w; w += 1024;
  float* abuf   = (float*)w; w += 1024;
  float* bbuf   = (float*)w; w += 1024;

  k_zero<<<dim3(2), dim3(256), 0, stream>>>(bnsum, 512);  // bnsum + bnsq
  k_w2<<<dim3(256), dim3(256), 0, stream>>>(t_w, v_w, v_b, w2, ub);
  k_wsplit<<<dim3(640), dim3(256), 0, stream>>>(q_w, k_w, w2, t_w, whb, wlb);
  k_xsplit<<<dim3(4, 256, NB), dim3(256), 0, stream>>>(x, xh, xl);
  k_projm<<<dim3(2, 256, NB), dim3(256), 0, stream>>>(xh, xl, whb, wlb, ub,
                                                      qh, ql, kh, kl, u, s);
  k_stats<<<dim3(16, NBK), dim3(256), 0, stream>>>(qh, ql, kh, kl, m_i, inv_l);
  k_denom<<<dim3(16, 16, NB), dim3(256), 0, stream>>>(qh, ql, kh, kl, m_i, inv_l, invden);
  k_xr<<<dim3(16, NBK), dim3(256), 0, stream>>>(qh, ql, kh, kl, (const u16*)u, m_i,
                                                inv_l, invden, txr);
  k_bnstats<<<dim3(NCHN, NB), dim3(256), 0, stream>>>(s, txr, t_b, bnsum, bnsq);
  k_bnfin<<<dim3(1), dim3(256), 0, stream>>>(bnsum, bnsq, gamma, beta, abuf, bbuf);
  k_out<<<dim3(NCHN, NB), dim3(256), 0, stream>>>(x, s, txr, t_b, abuf, bbuf, out);
}